// Round 1
// baseline (1742.577 us; speedup 1.0000x reference)
//
#include <hip/hip_runtime.h>

// VariationalGCNEncoder: 2-layer GCN (512 -> 4 -> [2,2]) on N=100k nodes, E=3.2M edges.
//
// Pipeline (all on `stream`):
//   k_init   : deg=1 (self loop), zero agg buffers
//   k_deg    : deg[dst] += 1 per edge (atomic)
//   k_dinv   : dinv = rsqrt(deg)
//   k_lin1   : h_lin = x @ W1            (wave-per-row, float4, shuffle reduce)
//   k_agg    : agg1[dst] += h_lin[src] * dinv[s]*dinv[d]   (edge scatter, atomics)
//   k_mid    : h = relu(agg1 + h_lin*dinv^2 + b1); t = h @ [W_mu | W_ls]
//   k_agg    : agg2[dst] += t[src] * dinv[s]*dinv[d]
//   k_out    : mu = agg2.xy + t.xy*dinv^2 + b_mu ; logstd = agg2.zw + t.zw*dinv^2 + b_ls

constexpr int N_NODES = 100000;
constexpr int N_EDGES = 3200000;
constexpr int IN_CH   = 512;

__global__ __launch_bounds__(256) void k_init(float* __restrict__ deg,
                                              float* __restrict__ agg1,
                                              float* __restrict__ agg2) {
    int i = blockIdx.x * blockDim.x + threadIdx.x;
    if (i < N_NODES) deg[i] = 1.0f;            // self-loop
    if (i < 4 * N_NODES) { agg1[i] = 0.0f; agg2[i] = 0.0f; }
}

__global__ __launch_bounds__(256) void k_deg(const int* __restrict__ dst,
                                             float* __restrict__ deg) {
    int e = blockIdx.x * blockDim.x + threadIdx.x;
    if (e >= N_EDGES) return;
    int d = dst[e];
    if ((unsigned)d < (unsigned)N_NODES) atomicAdd(&deg[d], 1.0f);
}

__global__ __launch_bounds__(256) void k_dinv(const float* __restrict__ deg,
                                              float* __restrict__ dinv) {
    int i = blockIdx.x * blockDim.x + threadIdx.x;
    if (i < N_NODES) dinv[i] = rsqrtf(deg[i]);   // deg >= 1 always (self loop)
}

// h_lin[row, 0:4] = x[row, :] @ W1   — one wave (64 lanes) per row.
// Each lane: 2 x float4 of x (8 elements), 8 float4s of W1 (channels per element).
__global__ __launch_bounds__(256) void k_lin1(const float* __restrict__ x,
                                              const float* __restrict__ W1,
                                              float* __restrict__ h) {
    int wave = threadIdx.x >> 6, lane = threadIdx.x & 63;
    int row = blockIdx.x * 4 + wave;
    if (row >= N_NODES) return;
    const float4* x4 = (const float4*)(x + (size_t)row * IN_CH);
    const float4* w4 = (const float4*)W1;   // w4[k] = 4 output channels of input elem k
    float4 acc = make_float4(0.f, 0.f, 0.f, 0.f);
#pragma unroll
    for (int j = 0; j < 2; ++j) {
        int idx = lane + 64 * j;
        float4 v = x4[idx];
        int kb = 4 * idx;
        float4 wa = w4[kb + 0], wb = w4[kb + 1], wc = w4[kb + 2], wd = w4[kb + 3];
        acc.x += v.x * wa.x + v.y * wb.x + v.z * wc.x + v.w * wd.x;
        acc.y += v.x * wa.y + v.y * wb.y + v.z * wc.y + v.w * wd.y;
        acc.z += v.x * wa.z + v.y * wb.z + v.z * wc.z + v.w * wd.z;
        acc.w += v.x * wa.w + v.y * wb.w + v.z * wc.w + v.w * wd.w;
    }
#pragma unroll
    for (int off = 32; off > 0; off >>= 1) {
        acc.x += __shfl_down(acc.x, off);
        acc.y += __shfl_down(acc.y, off);
        acc.z += __shfl_down(acc.z, off);
        acc.w += __shfl_down(acc.w, off);
    }
    if (lane == 0) ((float4*)h)[row] = acc;
}

// out[dst] += feat[src] * dinv[src]*dinv[dst]  over all E edges (self loops excluded;
// handled analytically in k_mid / k_out).
__global__ __launch_bounds__(256) void k_agg(const int* __restrict__ src,
                                             const int* __restrict__ dst,
                                             const float* __restrict__ dinv,
                                             const float* __restrict__ feat,
                                             float* __restrict__ out) {
    int e = blockIdx.x * blockDim.x + threadIdx.x;
    if (e >= N_EDGES) return;
    int s = src[e], d = dst[e];
    if ((unsigned)s >= (unsigned)N_NODES || (unsigned)d >= (unsigned)N_NODES) return;
    float w = dinv[s] * dinv[d];
    float4 f = ((const float4*)feat)[s];
    atomicAdd(&out[d * 4 + 0], f.x * w);
    atomicAdd(&out[d * 4 + 1], f.y * w);
    atomicAdd(&out[d * 4 + 2], f.z * w);
    atomicAdd(&out[d * 4 + 3], f.w * w);
}

// h = relu(agg1 + h_lin*dinv^2 + b1);  t = h @ [W_mu(4x2) | W_ls(4x2)]
__global__ __launch_bounds__(256) void k_mid(const float* __restrict__ agg1,
                                             const float* __restrict__ hlin,
                                             const float* __restrict__ dinv,
                                             const float* __restrict__ b1,
                                             const float* __restrict__ Wmu,
                                             const float* __restrict__ Wls,
                                             float* __restrict__ t) {
    int i = blockIdx.x * blockDim.x + threadIdx.x;
    if (i >= N_NODES) return;
    float di = dinv[i], d2 = di * di;
    float4 a  = ((const float4*)agg1)[i];
    float4 hl = ((const float4*)hlin)[i];
    float h0 = fmaxf(a.x + hl.x * d2 + b1[0], 0.f);
    float h1 = fmaxf(a.y + hl.y * d2 + b1[1], 0.f);
    float h2 = fmaxf(a.z + hl.z * d2 + b1[2], 0.f);
    float h3 = fmaxf(a.w + hl.w * d2 + b1[3], 0.f);
    float4 o;
    o.x = h0 * Wmu[0] + h1 * Wmu[2] + h2 * Wmu[4] + h3 * Wmu[6];
    o.y = h0 * Wmu[1] + h1 * Wmu[3] + h2 * Wmu[5] + h3 * Wmu[7];
    o.z = h0 * Wls[0] + h1 * Wls[2] + h2 * Wls[4] + h3 * Wls[6];
    o.w = h0 * Wls[1] + h1 * Wls[3] + h2 * Wls[5] + h3 * Wls[7];
    ((float4*)t)[i] = o;
}

__global__ __launch_bounds__(256) void k_out(const float* __restrict__ agg2,
                                             const float* __restrict__ t,
                                             const float* __restrict__ dinv,
                                             const float* __restrict__ bmu,
                                             const float* __restrict__ bls,
                                             float* __restrict__ out) {
    int i = blockIdx.x * blockDim.x + threadIdx.x;
    if (i >= N_NODES) return;
    float di = dinv[i], d2 = di * di;
    float4 a  = ((const float4*)agg2)[i];
    float4 ti = ((const float4*)t)[i];
    float2 mu = make_float2(a.x + ti.x * d2 + bmu[0], a.y + ti.y * d2 + bmu[1]);
    float2 ls = make_float2(a.z + ti.z * d2 + bls[0], a.w + ti.w * d2 + bls[1]);
    ((float2*)out)[i] = mu;                         // mu:     out[0 .. 2N)
    ((float2*)(out + 2 * N_NODES))[i] = ls;         // logstd: out[2N .. 4N)
}

extern "C" void kernel_launch(void* const* d_in, const int* in_sizes, int n_in,
                              void* d_out, int out_size, void* d_ws, size_t ws_size,
                              hipStream_t stream) {
    const float* x    = (const float*)d_in[0];
    const int*   ei   = (const int*)d_in[1];    // [2, E]: src row then dst row
    const float* W1   = (const float*)d_in[2];
    const float* b1   = (const float*)d_in[3];
    const float* Wmu  = (const float*)d_in[4];
    const float* bmu  = (const float*)d_in[5];
    const float* Wls  = (const float*)d_in[6];
    const float* bls  = (const float*)d_in[7];
    float* out = (float*)d_out;

    const int* src = ei;
    const int* dst = ei + N_EDGES;

    // workspace layout (floats)
    float* ws   = (float*)d_ws;
    float* deg  = ws;                  // [N]
    float* dinv = ws + 1 * N_NODES;    // [N]
    float* hlin = ws + 2 * N_NODES;    // [N,4]
    float* agg1 = ws + 6 * N_NODES;    // [N,4]
    float* t    = ws + 10 * N_NODES;   // [N,4]
    float* agg2 = ws + 14 * N_NODES;   // [N,4]

    const int TB = 256;
    int gN  = (N_NODES + TB - 1) / TB;            // 391
    int g4N = (4 * N_NODES + TB - 1) / TB;        // 1563
    int gE  = (N_EDGES + TB - 1) / TB;            // 12500
    int gL  = (N_NODES + 3) / 4;                  // 25000 (4 rows/block)

    k_init<<<g4N, TB, 0, stream>>>(deg, agg1, agg2);
    k_deg <<<gE,  TB, 0, stream>>>(dst, deg);
    k_dinv<<<gN,  TB, 0, stream>>>(deg, dinv);
    k_lin1<<<gL,  TB, 0, stream>>>(x, W1, hlin);
    k_agg <<<gE,  TB, 0, stream>>>(src, dst, dinv, hlin, agg1);
    k_mid <<<gN,  TB, 0, stream>>>(agg1, hlin, dinv, b1, Wmu, Wls, t);
    k_agg <<<gE,  TB, 0, stream>>>(src, dst, dinv, t, agg2);
    k_out <<<gN,  TB, 0, stream>>>(agg2, t, dinv, bmu, bls, out);
}

// Round 2
// 790.411 us; speedup vs baseline: 2.2046x; 2.2046x over previous
//
#include <hip/hip_runtime.h>

// VariationalGCNEncoder: 2-layer GCN (512 -> 4 -> [2,2]), N=100k nodes, E=3.2M edges.
//
// R2: replace float-atomic scatter (was 2x643us, 12.8M atomics each) with a
// per-call CSR build (counting sort by dst) + atomic-free gather passes.
//
//   k_zero    : cnt = 0
//   k_hist    : cnt[dst]++                       (3.2M int atomics)
//   k_scan1/2/3: exclusive scan -> offs, cursor; dinv = rsqrt(cnt+1)
//   k_scatter : ssrc[atomicAdd(cursor[d],1)] = s (3.2M int atomics)
//   k_lin1    : hlin = x @ W1                    (wave-per-row, float4)
//   k_gather1 : per node: sum_{in-edges} hlin[s]*dinv[s]*dinv[d] + self
//               -> relu(+b1) -> t = h @ [W_mu|W_ls]        (no atomics)
//   k_gather2 : same aggregation on t -> mu, logstd -> d_out

constexpr int N_NODES = 100000;
constexpr int N_EDGES = 3200000;
constexpr int IN_CH   = 512;
constexpr int SCAN_CHUNK = 2048;                    // 256 threads x 8
constexpr int NB_SCAN = (N_NODES + SCAN_CHUNK - 1) / SCAN_CHUNK;   // 49

__global__ __launch_bounds__(256) void k_zero(int* __restrict__ cnt) {
    int i = blockIdx.x * blockDim.x + threadIdx.x;
    if (i < N_NODES) cnt[i] = 0;
}

__global__ __launch_bounds__(256) void k_hist(const int* __restrict__ dst,
                                              int* __restrict__ cnt) {
    int e = blockIdx.x * blockDim.x + threadIdx.x;
    if (e >= N_EDGES) return;
    int d = dst[e];
    if ((unsigned)d < (unsigned)N_NODES) atomicAdd(&cnt[d], 1);
}

// Per-chunk exclusive scan; chunk totals to bsum.
__global__ __launch_bounds__(256) void k_scan1(const int* __restrict__ cnt,
                                               int* __restrict__ offs,
                                               int* __restrict__ bsum) {
    __shared__ int sdata[256];
    int tid = threadIdx.x;
    int base = blockIdx.x * SCAN_CHUNK + tid * 8;
    int v[8]; int s = 0;
#pragma unroll
    for (int j = 0; j < 8; ++j) {
        int idx = base + j;
        v[j] = (idx < N_NODES) ? cnt[idx] : 0;
        s += v[j];
    }
    sdata[tid] = s;
    __syncthreads();
    for (int off = 1; off < 256; off <<= 1) {
        int t = (tid >= off) ? sdata[tid - off] : 0;
        __syncthreads();
        sdata[tid] += t;
        __syncthreads();
    }
    int run = sdata[tid] - s;                 // exclusive within chunk
    if (tid == 255) bsum[blockIdx.x] = sdata[255];
#pragma unroll
    for (int j = 0; j < 8; ++j) {
        int idx = base + j;
        if (idx < N_NODES) offs[idx] = run;
        run += v[j];
    }
}

__global__ void k_scan2(int* __restrict__ bsum) {
    if (threadIdx.x == 0 && blockIdx.x == 0) {
        int run = 0;
        for (int b = 0; b < NB_SCAN; ++b) { int t = bsum[b]; bsum[b] = run; run += t; }
    }
}

__global__ __launch_bounds__(256) void k_scan3(int* __restrict__ offs,
                                               int* __restrict__ cursor,
                                               const int* __restrict__ bsum,
                                               const int* __restrict__ cnt,
                                               float* __restrict__ dinv) {
    int i = blockIdx.x * blockDim.x + threadIdx.x;
    if (i >= N_NODES) return;
    int off = offs[i] + bsum[i / SCAN_CHUNK];
    offs[i] = off;
    cursor[i] = off;
    dinv[i] = rsqrtf((float)(cnt[i] + 1));    // +1 self loop
}

__global__ __launch_bounds__(256) void k_scatter(const int* __restrict__ src,
                                                 const int* __restrict__ dst,
                                                 int* __restrict__ cursor,
                                                 int* __restrict__ ssrc) {
    int e = blockIdx.x * blockDim.x + threadIdx.x;
    if (e >= N_EDGES) return;
    int s = src[e], d = dst[e];
    if ((unsigned)s >= (unsigned)N_NODES || (unsigned)d >= (unsigned)N_NODES) return;
    int pos = atomicAdd(&cursor[d], 1);
    ssrc[pos] = s;
}

// hlin[row, 0:4] = x[row, :] @ W1 — one wave per row, float4 loads, shuffle reduce.
__global__ __launch_bounds__(256) void k_lin1(const float* __restrict__ x,
                                              const float* __restrict__ W1,
                                              float* __restrict__ h) {
    int wave = threadIdx.x >> 6, lane = threadIdx.x & 63;
    int row = blockIdx.x * 4 + wave;
    if (row >= N_NODES) return;
    const float4* x4 = (const float4*)(x + (size_t)row * IN_CH);
    const float4* w4 = (const float4*)W1;
    float4 acc = make_float4(0.f, 0.f, 0.f, 0.f);
#pragma unroll
    for (int j = 0; j < 2; ++j) {
        int idx = lane + 64 * j;
        float4 v = x4[idx];
        int kb = 4 * idx;
        float4 wa = w4[kb + 0], wb = w4[kb + 1], wc = w4[kb + 2], wd = w4[kb + 3];
        acc.x += v.x * wa.x + v.y * wb.x + v.z * wc.x + v.w * wd.x;
        acc.y += v.x * wa.y + v.y * wb.y + v.z * wc.y + v.w * wd.y;
        acc.z += v.x * wa.z + v.y * wb.z + v.z * wc.z + v.w * wd.z;
        acc.w += v.x * wa.w + v.y * wb.w + v.z * wc.w + v.w * wd.w;
    }
#pragma unroll
    for (int off = 32; off > 0; off >>= 1) {
        acc.x += __shfl_down(acc.x, off);
        acc.y += __shfl_down(acc.y, off);
        acc.z += __shfl_down(acc.z, off);
        acc.w += __shfl_down(acc.w, off);
    }
    if (lane == 0) ((float4*)h)[row] = acc;
}

// Layer-1 aggregate + relu + 4x4 linear to t = [mu_pre | ls_pre] per node.
__global__ __launch_bounds__(256) void k_gather1(const int* __restrict__ offs,
                                                 const int* __restrict__ cnt,
                                                 const int* __restrict__ ssrc,
                                                 const float* __restrict__ dinv,
                                                 const float* __restrict__ hlin,
                                                 const float* __restrict__ b1,
                                                 const float* __restrict__ Wmu,
                                                 const float* __restrict__ Wls,
                                                 float* __restrict__ t) {
    int i = blockIdx.x * blockDim.x + threadIdx.x;
    if (i >= N_NODES) return;
    float di = dinv[i];
    const float4* f4 = (const float4*)hlin;
    float4 hl = f4[i];
    float d2 = di * di;
    float4 acc = make_float4(hl.x * d2, hl.y * d2, hl.z * d2, hl.w * d2);  // self loop
    int st = offs[i], c = cnt[i];
    for (int j = 0; j < c; ++j) {
        int s = ssrc[st + j];
        float w = dinv[s] * di;
        float4 f = f4[s];
        acc.x += f.x * w; acc.y += f.y * w; acc.z += f.z * w; acc.w += f.w * w;
    }
    float h0 = fmaxf(acc.x + b1[0], 0.f);
    float h1 = fmaxf(acc.y + b1[1], 0.f);
    float h2 = fmaxf(acc.z + b1[2], 0.f);
    float h3 = fmaxf(acc.w + b1[3], 0.f);
    float4 o;
    o.x = h0 * Wmu[0] + h1 * Wmu[2] + h2 * Wmu[4] + h3 * Wmu[6];
    o.y = h0 * Wmu[1] + h1 * Wmu[3] + h2 * Wmu[5] + h3 * Wmu[7];
    o.z = h0 * Wls[0] + h1 * Wls[2] + h2 * Wls[4] + h3 * Wls[6];
    o.w = h0 * Wls[1] + h1 * Wls[3] + h2 * Wls[5] + h3 * Wls[7];
    ((float4*)t)[i] = o;
}

// Layer-2 aggregate on t -> mu (out[0..2N)), logstd (out[2N..4N)).
__global__ __launch_bounds__(256) void k_gather2(const int* __restrict__ offs,
                                                 const int* __restrict__ cnt,
                                                 const int* __restrict__ ssrc,
                                                 const float* __restrict__ dinv,
                                                 const float* __restrict__ t,
                                                 const float* __restrict__ bmu,
                                                 const float* __restrict__ bls,
                                                 float* __restrict__ out) {
    int i = blockIdx.x * blockDim.x + threadIdx.x;
    if (i >= N_NODES) return;
    float di = dinv[i];
    const float4* f4 = (const float4*)t;
    float4 ti = f4[i];
    float d2 = di * di;
    float4 acc = make_float4(ti.x * d2, ti.y * d2, ti.z * d2, ti.w * d2);  // self loop
    int st = offs[i], c = cnt[i];
    for (int j = 0; j < c; ++j) {
        int s = ssrc[st + j];
        float w = dinv[s] * di;
        float4 f = f4[s];
        acc.x += f.x * w; acc.y += f.y * w; acc.z += f.z * w; acc.w += f.w * w;
    }
    float2 mu = make_float2(acc.x + bmu[0], acc.y + bmu[1]);
    float2 ls = make_float2(acc.z + bls[0], acc.w + bls[1]);
    ((float2*)out)[i] = mu;
    ((float2*)(out + 2 * N_NODES))[i] = ls;
}

extern "C" void kernel_launch(void* const* d_in, const int* in_sizes, int n_in,
                              void* d_out, int out_size, void* d_ws, size_t ws_size,
                              hipStream_t stream) {
    const float* x    = (const float*)d_in[0];
    const int*   ei   = (const int*)d_in[1];    // [2, E] int32: src row then dst row
    const float* W1   = (const float*)d_in[2];
    const float* b1   = (const float*)d_in[3];
    const float* Wmu  = (const float*)d_in[4];
    const float* bmu  = (const float*)d_in[5];
    const float* Wls  = (const float*)d_in[6];
    const float* bls  = (const float*)d_in[7];
    float* out = (float*)d_out;

    const int* src = ei;
    const int* dst = ei + N_EDGES;

    // workspace layout
    char* p = (char*)d_ws;
    float* dinv  = (float*)p;  p += (size_t)N_NODES * 4;
    float* hlin  = (float*)p;  p += (size_t)N_NODES * 16;
    float* t     = (float*)p;  p += (size_t)N_NODES * 16;
    int*   cnt   = (int*)p;    p += (size_t)N_NODES * 4;
    int*   offs  = (int*)p;    p += (size_t)N_NODES * 4;
    int*   cursor= (int*)p;    p += (size_t)N_NODES * 4;
    int*   bsum  = (int*)p;    p += 256 * 4;
    int*   ssrc  = (int*)p;    p += (size_t)N_EDGES * 4;   // ~17.5 MB total

    const int TB = 256;
    int gN = (N_NODES + TB - 1) / TB;     // 391
    int gE = (N_EDGES + TB - 1) / TB;     // 12500
    int gL = (N_NODES + 3) / 4;           // 25000

    k_zero   <<<gN,      TB, 0, stream>>>(cnt);
    k_hist   <<<gE,      TB, 0, stream>>>(dst, cnt);
    k_scan1  <<<NB_SCAN, TB, 0, stream>>>(cnt, offs, bsum);
    k_scan2  <<<1,       64, 0, stream>>>(bsum);
    k_scan3  <<<gN,      TB, 0, stream>>>(offs, cursor, bsum, cnt, dinv);
    k_scatter<<<gE,      TB, 0, stream>>>(src, dst, cursor, ssrc);
    k_lin1   <<<gL,      TB, 0, stream>>>(x, W1, hlin);
    k_gather1<<<gN,      TB, 0, stream>>>(offs, cnt, ssrc, dinv, hlin, b1, Wmu, Wls, t);
    k_gather2<<<gN,      TB, 0, stream>>>(offs, cnt, ssrc, dinv, t, bmu, bls, out);
}

// Round 3
// 556.061 us; speedup vs baseline: 3.1338x; 1.4214x over previous
//
#include <hip/hip_runtime.h>

// VariationalGCNEncoder: 2-layer GCN (512 -> 4 -> [2,2]), N=100k nodes, E=3.2M edges.
//
// R3: eliminate random-line-granule traffic (R2's k_scatter: 195MB WRITE_SIZE for
// 12.8MB payload). Edges are partitioned into dst-buckets of 64 nodes; all random
// accumulation happens in LDS. No global float atomics anywhere.
//
//   k_zero  : zero bucket histogram
//   k_bhist : bucket sizes (LDS hist, 1 global atomic per (block,bucket))
//   k_bscan : exclusive scan over K=1563 buckets -> bbase, bcursor
//   k_part  : partition edges into buckets; packed entry = (s<<6)|(d&63)
//   k_count : per-bucket LDS node histogram -> dinv = rsqrt(deg+1)
//   k_lin1  : hlin = x @ W1 (wave-per-row, float4, shuffle reduce)
//   k_agg1  : WG-per-bucket LDS accumulate -> relu(+b1) -> t = h @ [W_mu|W_ls]
//   k_agg2  : same aggregation on t -> mu, logstd -> d_out

constexpr int N_NODES = 100000;
constexpr int N_EDGES = 3200000;
constexpr int IN_CH   = 512;
constexpr int BSH = 6;                         // 64 nodes per bucket
constexpr int NPB = 1 << BSH;                  // 64
constexpr int KB  = (N_NODES + NPB - 1) / NPB; // 1563 buckets
constexpr int PART_EPT = 16;                   // edges per thread in k_part
constexpr int PART_CHUNK = 256 * PART_EPT;     // 4096

__global__ __launch_bounds__(256) void k_zero(int* __restrict__ bhist) {
    int i = blockIdx.x * blockDim.x + threadIdx.x;
    if (i < KB) bhist[i] = 0;
}

__global__ __launch_bounds__(256) void k_bhist(const int* __restrict__ src,
                                               const int* __restrict__ dst,
                                               int* __restrict__ bhist) {
    __shared__ int h[KB];
    int tid = threadIdx.x;
    for (int i = tid; i < KB; i += 256) h[i] = 0;
    __syncthreads();
    int stride = gridDim.x * 256;
    for (int e = blockIdx.x * 256 + tid; e < N_EDGES; e += stride) {
        int s = src[e], d = dst[e];
        if ((unsigned)s < (unsigned)N_NODES && (unsigned)d < (unsigned)N_NODES)
            atomicAdd(&h[d >> BSH], 1);
    }
    __syncthreads();
    for (int i = tid; i < KB; i += 256) {
        int c = h[i];
        if (c) atomicAdd(&bhist[i], c);
    }
}

// Single-block exclusive scan over KB bucket sizes.
__global__ __launch_bounds__(256) void k_bscan(const int* __restrict__ bhist,
                                               int* __restrict__ bbase,
                                               int* __restrict__ bcursor) {
    constexpr int PT = (KB + 255) / 256;   // 7
    __shared__ int part[256];
    int tid = threadIdx.x;
    int v[PT]; int s = 0;
    int base = tid * PT;
#pragma unroll
    for (int j = 0; j < PT; ++j) {
        int idx = base + j;
        v[j] = (idx < KB) ? bhist[idx] : 0;
        s += v[j];
    }
    part[tid] = s;
    __syncthreads();
    for (int off = 1; off < 256; off <<= 1) {
        int t = (tid >= off) ? part[tid - off] : 0;
        __syncthreads();
        part[tid] += t;
        __syncthreads();
    }
    int run = part[tid] - s;
#pragma unroll
    for (int j = 0; j < PT; ++j) {
        int idx = base + j;
        if (idx < KB) { bbase[idx] = run; bcursor[idx] = run; }
        run += v[j];
    }
}

// Partition edges into dst-buckets. Packed entry: (s << 6) | (d & 63); s < 2^17.
__global__ __launch_bounds__(256) void k_part(const int* __restrict__ src,
                                              const int* __restrict__ dst,
                                              int* __restrict__ bcursor,
                                              int* __restrict__ ebuf) {
    __shared__ int lbase[KB];
    int tid = threadIdx.x;
    for (int i = tid; i < KB; i += 256) lbase[i] = 0;
    __syncthreads();
    int start = blockIdx.x * PART_CHUNK;
    int rr[PART_EPT];   // (rank << 17) | d
    int ss[PART_EPT];   // src, or -1 if invalid
#pragma unroll
    for (int j = 0; j < PART_EPT; ++j) {
        int e = start + j * 256 + tid;
        ss[j] = -1;
        if (e < N_EDGES) {
            int s = src[e], d = dst[e];
            if ((unsigned)s < (unsigned)N_NODES && (unsigned)d < (unsigned)N_NODES) {
                int r = atomicAdd(&lbase[d >> BSH], 1);
                rr[j] = (r << 17) | d;
                ss[j] = s;
            }
        }
    }
    __syncthreads();
    for (int i = tid; i < KB; i += 256) {
        int c = lbase[i];
        if (c) lbase[i] = atomicAdd(&bcursor[i], c);
    }
    __syncthreads();
#pragma unroll
    for (int j = 0; j < PART_EPT; ++j) {
        if (ss[j] >= 0) {
            int d = rr[j] & 0x1FFFF;
            int r = rr[j] >> 17;
            int b = d >> BSH;
            ebuf[lbase[b] + r] = (ss[j] << BSH) | (d & (NPB - 1));
        }
    }
}

// Per-bucket node degree -> dinv = rsqrt(deg + 1).
__global__ __launch_bounds__(256) void k_count(const int* __restrict__ ebuf,
                                               const int* __restrict__ bbase,
                                               const int* __restrict__ bhist,
                                               float* __restrict__ dinv) {
    __shared__ int c[NPB];
    int b = blockIdx.x, tid = threadIdx.x;
    if (tid < NPB) c[tid] = 0;
    __syncthreads();
    int st = bbase[b], en = st + bhist[b];
    for (int j = st + tid; j < en; j += 256)
        atomicAdd(&c[ebuf[j] & (NPB - 1)], 1);
    __syncthreads();
    if (tid < NPB) {
        int node = b * NPB + tid;
        if (node < N_NODES) dinv[node] = rsqrtf((float)(c[tid] + 1));
    }
}

// hlin[row, 0:4] = x[row, :] @ W1 — one wave per row, float4 loads, shuffle reduce.
__global__ __launch_bounds__(256) void k_lin1(const float* __restrict__ x,
                                              const float* __restrict__ W1,
                                              float* __restrict__ h) {
    int wave = threadIdx.x >> 6, lane = threadIdx.x & 63;
    int row = blockIdx.x * 4 + wave;
    if (row >= N_NODES) return;
    const float4* x4 = (const float4*)(x + (size_t)row * IN_CH);
    const float4* w4 = (const float4*)W1;
    float4 acc = make_float4(0.f, 0.f, 0.f, 0.f);
#pragma unroll
    for (int j = 0; j < 2; ++j) {
        int idx = lane + 64 * j;
        float4 v = x4[idx];
        int kb = 4 * idx;
        float4 wa = w4[kb + 0], wb = w4[kb + 1], wc = w4[kb + 2], wd = w4[kb + 3];
        acc.x += v.x * wa.x + v.y * wb.x + v.z * wc.x + v.w * wd.x;
        acc.y += v.x * wa.y + v.y * wb.y + v.z * wc.y + v.w * wd.y;
        acc.z += v.x * wa.z + v.y * wb.z + v.z * wc.z + v.w * wd.z;
        acc.w += v.x * wa.w + v.y * wb.w + v.z * wc.w + v.w * wd.w;
    }
#pragma unroll
    for (int off = 32; off > 0; off >>= 1) {
        acc.x += __shfl_down(acc.x, off);
        acc.y += __shfl_down(acc.y, off);
        acc.z += __shfl_down(acc.z, off);
        acc.w += __shfl_down(acc.w, off);
    }
    if (lane == 0) ((float4*)h)[row] = acc;
}

// Layer-1 aggregation (WG per bucket, LDS accumulators) + relu + t = h @ [W_mu|W_ls].
__global__ __launch_bounds__(256) void k_agg1(const int* __restrict__ ebuf,
                                              const int* __restrict__ bbase,
                                              const int* __restrict__ bhist,
                                              const float* __restrict__ dinv,
                                              const float* __restrict__ hlin,
                                              const float* __restrict__ b1,
                                              const float* __restrict__ Wmu,
                                              const float* __restrict__ Wls,
                                              float* __restrict__ t) {
    __shared__ float acc[NPB * 5];     // stride 5 to spread LDS banks
    __shared__ float dlo[NPB];
    int b = blockIdx.x, tid = threadIdx.x;
    for (int i = tid; i < NPB * 5; i += 256) acc[i] = 0.f;
    if (tid < NPB) {
        int node = b * NPB + tid;
        dlo[tid] = (node < N_NODES) ? dinv[node] : 0.f;
    }
    __syncthreads();
    const float4* f4 = (const float4*)hlin;
    int st = bbase[b], en = st + bhist[b];
    for (int j = st + tid; j < en; j += 256) {
        int e = ebuf[j];
        int s = e >> BSH, dl = e & (NPB - 1);
        float w = dinv[s] * dlo[dl];
        float4 f = f4[s];
        atomicAdd(&acc[dl * 5 + 0], f.x * w);
        atomicAdd(&acc[dl * 5 + 1], f.y * w);
        atomicAdd(&acc[dl * 5 + 2], f.z * w);
        atomicAdd(&acc[dl * 5 + 3], f.w * w);
    }
    __syncthreads();
    if (tid < NPB) {
        int node = b * NPB + tid;
        if (node < N_NODES) {
            float di = dlo[tid], d2 = di * di;
            float4 hl = f4[node];
            float h0 = fmaxf(acc[tid * 5 + 0] + hl.x * d2 + b1[0], 0.f);
            float h1 = fmaxf(acc[tid * 5 + 1] + hl.y * d2 + b1[1], 0.f);
            float h2 = fmaxf(acc[tid * 5 + 2] + hl.z * d2 + b1[2], 0.f);
            float h3 = fmaxf(acc[tid * 5 + 3] + hl.w * d2 + b1[3], 0.f);
            float4 o;
            o.x = h0 * Wmu[0] + h1 * Wmu[2] + h2 * Wmu[4] + h3 * Wmu[6];
            o.y = h0 * Wmu[1] + h1 * Wmu[3] + h2 * Wmu[5] + h3 * Wmu[7];
            o.z = h0 * Wls[0] + h1 * Wls[2] + h2 * Wls[4] + h3 * Wls[6];
            o.w = h0 * Wls[1] + h1 * Wls[3] + h2 * Wls[5] + h3 * Wls[7];
            ((float4*)t)[node] = o;
        }
    }
}

// Layer-2 aggregation on t -> mu (out[0..2N)), logstd (out[2N..4N)).
__global__ __launch_bounds__(256) void k_agg2(const int* __restrict__ ebuf,
                                              const int* __restrict__ bbase,
                                              const int* __restrict__ bhist,
                                              const float* __restrict__ dinv,
                                              const float* __restrict__ t,
                                              const float* __restrict__ bmu,
                                              const float* __restrict__ bls,
                                              float* __restrict__ out) {
    __shared__ float acc[NPB * 5];
    __shared__ float dlo[NPB];
    int b = blockIdx.x, tid = threadIdx.x;
    for (int i = tid; i < NPB * 5; i += 256) acc[i] = 0.f;
    if (tid < NPB) {
        int node = b * NPB + tid;
        dlo[tid] = (node < N_NODES) ? dinv[node] : 0.f;
    }
    __syncthreads();
    const float4* f4 = (const float4*)t;
    int st = bbase[b], en = st + bhist[b];
    for (int j = st + tid; j < en; j += 256) {
        int e = ebuf[j];
        int s = e >> BSH, dl = e & (NPB - 1);
        float w = dinv[s] * dlo[dl];
        float4 f = f4[s];
        atomicAdd(&acc[dl * 5 + 0], f.x * w);
        atomicAdd(&acc[dl * 5 + 1], f.y * w);
        atomicAdd(&acc[dl * 5 + 2], f.z * w);
        atomicAdd(&acc[dl * 5 + 3], f.w * w);
    }
    __syncthreads();
    if (tid < NPB) {
        int node = b * NPB + tid;
        if (node < N_NODES) {
            float di = dlo[tid], d2 = di * di;
            float4 ti = f4[node];
            float2 mu = make_float2(acc[tid * 5 + 0] + ti.x * d2 + bmu[0],
                                    acc[tid * 5 + 1] + ti.y * d2 + bmu[1]);
            float2 ls = make_float2(acc[tid * 5 + 2] + ti.z * d2 + bls[0],
                                    acc[tid * 5 + 3] + ti.w * d2 + bls[1]);
            ((float2*)out)[node] = mu;
            ((float2*)(out + 2 * N_NODES))[node] = ls;
        }
    }
}

extern "C" void kernel_launch(void* const* d_in, const int* in_sizes, int n_in,
                              void* d_out, int out_size, void* d_ws, size_t ws_size,
                              hipStream_t stream) {
    const float* x    = (const float*)d_in[0];
    const int*   ei   = (const int*)d_in[1];    // [2, E] int32: src row then dst row
    const float* W1   = (const float*)d_in[2];
    const float* b1   = (const float*)d_in[3];
    const float* Wmu  = (const float*)d_in[4];
    const float* bmu  = (const float*)d_in[5];
    const float* Wls  = (const float*)d_in[6];
    const float* bls  = (const float*)d_in[7];
    float* out = (float*)d_out;

    const int* src = ei;
    const int* dst = ei + N_EDGES;

    // workspace layout (~16.5 MB)
    char* p = (char*)d_ws;
    float* dinv  = (float*)p;  p += (size_t)N_NODES * 4;
    float* hlin  = (float*)p;  p += (size_t)N_NODES * 16;
    float* t     = (float*)p;  p += (size_t)N_NODES * 16;
    int*   bhist = (int*)p;    p += (size_t)KB * 4;
    int*   bbase = (int*)p;    p += (size_t)KB * 4;
    int*   bcur  = (int*)p;    p += (size_t)KB * 4;
    int*   ebuf  = (int*)p;    p += (size_t)N_EDGES * 4;

    const int TB = 256;
    int gK = (KB + TB - 1) / TB;                         // 7
    int gP = (N_EDGES + PART_CHUNK - 1) / PART_CHUNK;    // 782
    int gL = (N_NODES + 3) / 4;                          // 25000

    k_zero <<<gK,  TB, 0, stream>>>(bhist);
    k_bhist<<<256, TB, 0, stream>>>(src, dst, bhist);
    k_bscan<<<1,   TB, 0, stream>>>(bhist, bbase, bcur);
    k_part <<<gP,  TB, 0, stream>>>(src, dst, bcur, ebuf);
    k_count<<<KB,  TB, 0, stream>>>(ebuf, bbase, bhist, dinv);
    k_lin1 <<<gL,  TB, 0, stream>>>(x, W1, hlin);
    k_agg1 <<<KB,  TB, 0, stream>>>(ebuf, bbase, bhist, dinv, hlin, b1, Wmu, Wls, t);
    k_agg2 <<<KB,  TB, 0, stream>>>(ebuf, bbase, bhist, dinv, t, bmu, bls, out);
}

// Round 4
// 410.424 us; speedup vs baseline: 4.2458x; 1.3548x over previous
//
#include <hip/hip_runtime.h>

// VariationalGCNEncoder: 2-layer GCN (512 -> 4 -> [2,2]), N=100k nodes, E=3.2M edges.
//
// R4: two-level counting sort (coarse by d>>8, then by-node inside an L2-resident
// 40KB window) -> per-node CSR; aggregation uses register accumulators (zero LDS
// atomics, zero global float atomics). Features pre-scaled by dinv so the per-edge
// work is a single float4 gather+add.
//
//   k_zero  : bcur[b] = b*CAP
//   k_part1 : coarse partition into 391 buckets of 256 nodes; packed (s<<8)|(d&255)
//   k_part2 : per-bucket node sort -> ebuf2 (src only), nstart/ncnt/dinv
//   k_lin1  : hls = (x @ W1) * dinv[row]         (wave-per-row, float4)
//   k_agg1  : per-node CSR gather (4 thr/node, reg acc) -> relu -> ts = (h@[Wmu|Wls])*dinv
//   k_agg2  : same on ts -> mu, logstd -> d_out

constexpr int N_NODES = 100000;
constexpr int N_EDGES = 3200000;
constexpr int IN_CH   = 512;
constexpr int CB_SH   = 8;                      // 256 nodes per coarse bucket
constexpr int CB_N    = 1 << CB_SH;
constexpr int KC      = (N_NODES + CB_N - 1) / CB_N;   // 391
constexpr int CAP     = 10240;                  // per-bucket capacity (mean 8192, sigma~90)
constexpr int P1_EPT  = 16;
constexpr int P1_CHUNK = 256 * P1_EPT;          // 4096

__global__ __launch_bounds__(256) void k_zero(int* __restrict__ bcur) {
    int i = blockIdx.x * blockDim.x + threadIdx.x;
    if (i < KC) bcur[i] = i * CAP;
}

// Coarse partition: ebuf1[bucket segment] <- (s<<8)|(d&255).
__global__ __launch_bounds__(256) void k_part1(const int* __restrict__ src,
                                               const int* __restrict__ dst,
                                               int* __restrict__ bcur,
                                               int* __restrict__ ebuf1) {
    __shared__ int lcnt[KC];
    int tid = threadIdx.x;
    for (int i = tid; i < KC; i += 256) lcnt[i] = 0;
    __syncthreads();
    int start = blockIdx.x * P1_CHUNK;
    int pk[P1_EPT];   // packed (s<<8)|(d&255)
    int rk[P1_EPT];   // (bucket<<13)|rank, or -1
#pragma unroll
    for (int j = 0; j < P1_EPT; ++j) {
        int e = start + j * 256 + tid;
        rk[j] = -1;
        if (e < N_EDGES) {
            int s = src[e], d = dst[e];
            if ((unsigned)s < (unsigned)N_NODES && (unsigned)d < (unsigned)N_NODES) {
                int b = d >> CB_SH;
                int r = atomicAdd(&lcnt[b], 1);       // rank < 4096 fits 13 bits
                pk[j] = (s << CB_SH) | (d & (CB_N - 1));
                rk[j] = (b << 13) | r;
            }
        }
    }
    __syncthreads();
    for (int i = tid; i < KC; i += 256) {
        int c = lcnt[i];
        lcnt[i] = c ? atomicAdd(&bcur[i], c) : 0;     // global base for this block's run
    }
    __syncthreads();
#pragma unroll
    for (int j = 0; j < P1_EPT; ++j) {
        if (rk[j] >= 0) {
            int b = rk[j] >> 13, r = rk[j] & 0x1FFF;
            // clamp guards capacity (statistically unreachable)
            int pos = lcnt[b] + r;
            if (pos < (b + 1) * CAP) ebuf1[pos] = pk[j];
        }
    }
}

// Per-bucket node sort inside 40KB window. Emits CSR (nstart/ncnt), dinv, ebuf2=src.
__global__ __launch_bounds__(256) void k_part2(const int* __restrict__ bcur,
                                               const int* __restrict__ ebuf1,
                                               int* __restrict__ ebuf2,
                                               int* __restrict__ nstart,
                                               int* __restrict__ ncnt,
                                               float* __restrict__ dinv) {
    __shared__ int sdata[CB_N];
    __shared__ int cur[CB_N];
    int b = blockIdx.x, tid = threadIdx.x;
    int base = b * CAP;
    int cnt_b = bcur[b] - base;
    sdata[tid] = 0;
    __syncthreads();
    for (int j = tid; j < cnt_b; j += 256)
        atomicAdd(&sdata[ebuf1[base + j] & (CB_N - 1)], 1);
    __syncthreads();
    int v = sdata[tid];
    // inclusive Hillis-Steele scan
    for (int off = 1; off < 256; off <<= 1) {
        int t = (tid >= off) ? sdata[tid - off] : 0;
        __syncthreads();
        sdata[tid] += t;
        __syncthreads();
    }
    int excl = sdata[tid] - v;
    cur[tid] = excl;
    int node = b * CB_N + tid;
    if (node < N_NODES) {
        nstart[node] = base + excl;
        ncnt[node]   = v;
        dinv[node]   = rsqrtf((float)(v + 1));   // +1 self loop
    }
    __syncthreads();
    for (int j = tid; j < cnt_b; j += 256) {
        int e = ebuf1[base + j];
        int dl = e & (CB_N - 1);
        int r = atomicAdd(&cur[dl], 1);
        ebuf2[base + r] = e >> CB_SH;            // src only; dst encoded by position
    }
}

// hls[row] = (x[row,:] @ W1) * dinv[row] — one wave per row, float4 loads.
__global__ __launch_bounds__(256) void k_lin1(const float* __restrict__ x,
                                              const float* __restrict__ W1,
                                              const float* __restrict__ dinv,
                                              float* __restrict__ h) {
    int wave = threadIdx.x >> 6, lane = threadIdx.x & 63;
    int row = blockIdx.x * 4 + wave;
    if (row >= N_NODES) return;
    const float4* x4 = (const float4*)(x + (size_t)row * IN_CH);
    const float4* w4 = (const float4*)W1;
    float4 acc = make_float4(0.f, 0.f, 0.f, 0.f);
#pragma unroll
    for (int j = 0; j < 2; ++j) {
        int idx = lane + 64 * j;
        float4 v = x4[idx];
        int kb = 4 * idx;
        float4 wa = w4[kb + 0], wb = w4[kb + 1], wc = w4[kb + 2], wd = w4[kb + 3];
        acc.x += v.x * wa.x + v.y * wb.x + v.z * wc.x + v.w * wd.x;
        acc.y += v.x * wa.y + v.y * wb.y + v.z * wc.y + v.w * wd.y;
        acc.z += v.x * wa.z + v.y * wb.z + v.z * wc.z + v.w * wd.z;
        acc.w += v.x * wa.w + v.y * wb.w + v.z * wc.w + v.w * wd.w;
    }
#pragma unroll
    for (int off = 32; off > 0; off >>= 1) {
        acc.x += __shfl_down(acc.x, off);
        acc.y += __shfl_down(acc.y, off);
        acc.z += __shfl_down(acc.z, off);
        acc.w += __shfl_down(acc.w, off);
    }
    if (lane == 0) {
        float di = dinv[row];
        ((float4*)h)[row] = make_float4(acc.x * di, acc.y * di, acc.z * di, acc.w * di);
    }
}

// Layer-1 aggregation: 4 threads per node, register accumulation, quad shuffle-combine.
// agg = dinv_d * (sum_{s in N(d)} hls[s] + hls[d]);  h=relu(agg+b1);  ts=(h@[Wmu|Wls])*dinv_d
__global__ __launch_bounds__(256) void k_agg1(const int* __restrict__ ebuf2,
                                              const int* __restrict__ nstart,
                                              const int* __restrict__ ncnt,
                                              const float* __restrict__ dinv,
                                              const float* __restrict__ hls,
                                              const float* __restrict__ b1,
                                              const float* __restrict__ Wmu,
                                              const float* __restrict__ Wls,
                                              float* __restrict__ ts) {
    int tid = threadIdx.x;
    int node = blockIdx.x * 64 + (tid >> 2);
    int r = tid & 3;
    if (node >= N_NODES) return;                 // quad-uniform exit
    const float4* g4 = (const float4*)hls;
    int st = nstart[node], c = ncnt[node];
    float4 a = make_float4(0.f, 0.f, 0.f, 0.f);
    for (int j = r; j < c; j += 4) {
        float4 f = g4[ebuf2[st + j]];
        a.x += f.x; a.y += f.y; a.z += f.z; a.w += f.w;
    }
    a.x += __shfl_xor(a.x, 1); a.y += __shfl_xor(a.y, 1);
    a.z += __shfl_xor(a.z, 1); a.w += __shfl_xor(a.w, 1);
    a.x += __shfl_xor(a.x, 2); a.y += __shfl_xor(a.y, 2);
    a.z += __shfl_xor(a.z, 2); a.w += __shfl_xor(a.w, 2);
    if (r == 0) {
        float4 self = g4[node];
        float di = dinv[node];
        float h0 = fmaxf((a.x + self.x) * di + b1[0], 0.f);
        float h1 = fmaxf((a.y + self.y) * di + b1[1], 0.f);
        float h2 = fmaxf((a.z + self.z) * di + b1[2], 0.f);
        float h3 = fmaxf((a.w + self.w) * di + b1[3], 0.f);
        float4 o;
        o.x = (h0 * Wmu[0] + h1 * Wmu[2] + h2 * Wmu[4] + h3 * Wmu[6]) * di;
        o.y = (h0 * Wmu[1] + h1 * Wmu[3] + h2 * Wmu[5] + h3 * Wmu[7]) * di;
        o.z = (h0 * Wls[0] + h1 * Wls[2] + h2 * Wls[4] + h3 * Wls[6]) * di;
        o.w = (h0 * Wls[1] + h1 * Wls[3] + h2 * Wls[5] + h3 * Wls[7]) * di;
        ((float4*)ts)[node] = o;
    }
}

// Layer-2 aggregation on ts -> mu (out[0..2N)), logstd (out[2N..4N)).
__global__ __launch_bounds__(256) void k_agg2(const int* __restrict__ ebuf2,
                                              const int* __restrict__ nstart,
                                              const int* __restrict__ ncnt,
                                              const float* __restrict__ dinv,
                                              const float* __restrict__ ts,
                                              const float* __restrict__ bmu,
                                              const float* __restrict__ bls,
                                              float* __restrict__ out) {
    int tid = threadIdx.x;
    int node = blockIdx.x * 64 + (tid >> 2);
    int r = tid & 3;
    if (node >= N_NODES) return;
    const float4* g4 = (const float4*)ts;
    int st = nstart[node], c = ncnt[node];
    float4 a = make_float4(0.f, 0.f, 0.f, 0.f);
    for (int j = r; j < c; j += 4) {
        float4 f = g4[ebuf2[st + j]];
        a.x += f.x; a.y += f.y; a.z += f.z; a.w += f.w;
    }
    a.x += __shfl_xor(a.x, 1); a.y += __shfl_xor(a.y, 1);
    a.z += __shfl_xor(a.z, 1); a.w += __shfl_xor(a.w, 1);
    a.x += __shfl_xor(a.x, 2); a.y += __shfl_xor(a.y, 2);
    a.z += __shfl_xor(a.z, 2); a.w += __shfl_xor(a.w, 2);
    if (r == 0) {
        float4 self = g4[node];
        float di = dinv[node];
        float2 mu = make_float2((a.x + self.x) * di + bmu[0],
                                (a.y + self.y) * di + bmu[1]);
        float2 ls = make_float2((a.z + self.z) * di + bls[0],
                                (a.w + self.w) * di + bls[1]);
        ((float2*)out)[node] = mu;
        ((float2*)(out + 2 * N_NODES))[node] = ls;
    }
}

extern "C" void kernel_launch(void* const* d_in, const int* in_sizes, int n_in,
                              void* d_out, int out_size, void* d_ws, size_t ws_size,
                              hipStream_t stream) {
    const float* x    = (const float*)d_in[0];
    const int*   ei   = (const int*)d_in[1];    // [2, E] int32: src row then dst row
    const float* W1   = (const float*)d_in[2];
    const float* b1   = (const float*)d_in[3];
    const float* Wmu  = (const float*)d_in[4];
    const float* bmu  = (const float*)d_in[5];
    const float* Wls  = (const float*)d_in[6];
    const float* bls  = (const float*)d_in[7];
    float* out = (float*)d_out;

    const int* src = ei;
    const int* dst = ei + N_EDGES;

    // workspace layout (~36 MB)
    char* p = (char*)d_ws;
    float* dinv   = (float*)p;  p += (size_t)N_NODES * 4;
    float* hls    = (float*)p;  p += (size_t)N_NODES * 16;
    float* ts     = (float*)p;  p += (size_t)N_NODES * 16;
    int*   nstart = (int*)p;    p += (size_t)N_NODES * 4;
    int*   ncnt   = (int*)p;    p += (size_t)N_NODES * 4;
    int*   bcur   = (int*)p;    p += (size_t)KC * 4;
    int*   ebuf1  = (int*)p;    p += (size_t)KC * CAP * 4;   // 16 MB
    int*   ebuf2  = (int*)p;    p += (size_t)KC * CAP * 4;   // 16 MB

    const int TB = 256;
    int gP1 = (N_EDGES + P1_CHUNK - 1) / P1_CHUNK;   // 782
    int gL  = (N_NODES + 3) / 4;                     // 25000
    int gA  = (N_NODES + 63) / 64;                   // 1563

    k_zero <<<(KC + TB - 1) / TB, TB, 0, stream>>>(bcur);
    k_part1<<<gP1, TB, 0, stream>>>(src, dst, bcur, ebuf1);
    k_part2<<<KC,  TB, 0, stream>>>(bcur, ebuf1, ebuf2, nstart, ncnt, dinv);
    k_lin1 <<<gL,  TB, 0, stream>>>(x, W1, dinv, hls);
    k_agg1 <<<gA,  TB, 0, stream>>>(ebuf2, nstart, ncnt, dinv, hls, b1, Wmu, Wls, ts);
    k_agg2 <<<gA,  TB, 0, stream>>>(ebuf2, nstart, ncnt, dinv, ts, bmu, bls, out);
}

// Round 5
// 396.719 us; speedup vs baseline: 4.3925x; 1.0345x over previous
//
#include <hip/hip_runtime.h>

// VariationalGCNEncoder: 2-layer GCN (512 -> 4 -> [2,2]), N=100k nodes, E=3.2M edges.
//
// R5: R4 structure (two-level counting sort -> per-node CSR -> register-accum
// gathers), with latency-hiding fixes:
//   - k_part2 at 1024 threads/block (was 256; 391 blocks -> was ~6 waves/CU)
//   - k_agg1/2 at 8 threads/node + 2x-unrolled dual-accumulator gather loop
//
//   k_zero  : bcur[b] = b*CAP
//   k_part1 : coarse partition into 391 buckets of 256 nodes; packed (s<<8)|(d&255)
//   k_part2 : per-bucket node sort -> ebuf2 (src only), nstart/ncnt/dinv
//   k_lin1  : hls = (x @ W1) * dinv[row]         (wave-per-row, float4)
//   k_agg1  : per-node CSR gather -> relu -> ts = (h@[Wmu|Wls])*dinv
//   k_agg2  : same on ts -> mu, logstd -> d_out

constexpr int N_NODES = 100000;
constexpr int N_EDGES = 3200000;
constexpr int IN_CH   = 512;
constexpr int CB_SH   = 8;                      // 256 nodes per coarse bucket
constexpr int CB_N    = 1 << CB_SH;
constexpr int KC      = (N_NODES + CB_N - 1) / CB_N;   // 391
constexpr int CAP     = 10240;                  // per-bucket capacity (mean 8192, sigma~90)
constexpr int P1_EPT  = 16;
constexpr int P1_CHUNK = 256 * P1_EPT;          // 4096

__global__ __launch_bounds__(256) void k_zero(int* __restrict__ bcur) {
    int i = blockIdx.x * blockDim.x + threadIdx.x;
    if (i < KC) bcur[i] = i * CAP;
}

// Coarse partition: ebuf1[bucket segment] <- (s<<8)|(d&255).
__global__ __launch_bounds__(256) void k_part1(const int* __restrict__ src,
                                               const int* __restrict__ dst,
                                               int* __restrict__ bcur,
                                               int* __restrict__ ebuf1) {
    __shared__ int lcnt[KC];
    int tid = threadIdx.x;
    for (int i = tid; i < KC; i += 256) lcnt[i] = 0;
    __syncthreads();
    int start = blockIdx.x * P1_CHUNK;
    int pk[P1_EPT];   // packed (s<<8)|(d&255)
    int rk[P1_EPT];   // (bucket<<13)|rank, or -1
#pragma unroll
    for (int j = 0; j < P1_EPT; ++j) {
        int e = start + j * 256 + tid;
        rk[j] = -1;
        if (e < N_EDGES) {
            int s = src[e], d = dst[e];
            if ((unsigned)s < (unsigned)N_NODES && (unsigned)d < (unsigned)N_NODES) {
                int b = d >> CB_SH;
                int r = atomicAdd(&lcnt[b], 1);       // rank < 4096 fits 13 bits
                pk[j] = (s << CB_SH) | (d & (CB_N - 1));
                rk[j] = (b << 13) | r;
            }
        }
    }
    __syncthreads();
    for (int i = tid; i < KC; i += 256) {
        int c = lcnt[i];
        lcnt[i] = c ? atomicAdd(&bcur[i], c) : 0;     // global base for this block's run
    }
    __syncthreads();
#pragma unroll
    for (int j = 0; j < P1_EPT; ++j) {
        if (rk[j] >= 0) {
            int b = rk[j] >> 13, r = rk[j] & 0x1FFF;
            int pos = lcnt[b] + r;
            if (pos < (b + 1) * CAP) ebuf1[pos] = pk[j];   // capacity guard (unreachable)
        }
    }
}

// Per-bucket node sort inside 40KB L2 window. Emits CSR (nstart/ncnt), dinv, ebuf2=src.
// 1024 threads: 16 waves/block for latency hiding (391 blocks total).
__global__ __launch_bounds__(1024) void k_part2(const int* __restrict__ bcur,
                                                const int* __restrict__ ebuf1,
                                                int* __restrict__ ebuf2,
                                                int* __restrict__ nstart,
                                                int* __restrict__ ncnt,
                                                float* __restrict__ dinv) {
    __shared__ int sdata[CB_N];
    __shared__ int cur[CB_N];
    int b = blockIdx.x, tid = threadIdx.x;
    int base = b * CAP;
    int cnt_b = bcur[b] - base;
    if (tid < CB_N) sdata[tid] = 0;
    __syncthreads();
    for (int j = tid; j < cnt_b; j += 1024)
        atomicAdd(&sdata[ebuf1[base + j] & (CB_N - 1)], 1);
    __syncthreads();
    int v = (tid < CB_N) ? sdata[tid] : 0;
    // inclusive Hillis-Steele scan over the 256 histogram entries (all threads sync)
    for (int off = 1; off < CB_N; off <<= 1) {
        int t = (tid >= off && tid < CB_N) ? sdata[tid - off] : 0;
        __syncthreads();
        if (tid < CB_N) sdata[tid] += t;
        __syncthreads();
    }
    if (tid < CB_N) {
        int excl = sdata[tid] - v;
        cur[tid] = excl;
        int node = b * CB_N + tid;
        if (node < N_NODES) {
            nstart[node] = base + excl;
            ncnt[node]   = v;
            dinv[node]   = rsqrtf((float)(v + 1));   // +1 self loop
        }
    }
    __syncthreads();
    for (int j = tid; j < cnt_b; j += 1024) {
        int e = ebuf1[base + j];
        int dl = e & (CB_N - 1);
        int r = atomicAdd(&cur[dl], 1);
        ebuf2[base + r] = e >> CB_SH;            // src only; dst encoded by position
    }
}

// hls[row] = (x[row,:] @ W1) * dinv[row] — one wave per row, float4 loads.
__global__ __launch_bounds__(256) void k_lin1(const float* __restrict__ x,
                                              const float* __restrict__ W1,
                                              const float* __restrict__ dinv,
                                              float* __restrict__ h) {
    int wave = threadIdx.x >> 6, lane = threadIdx.x & 63;
    int row = blockIdx.x * 4 + wave;
    if (row >= N_NODES) return;
    const float4* x4 = (const float4*)(x + (size_t)row * IN_CH);
    const float4* w4 = (const float4*)W1;
    float4 acc = make_float4(0.f, 0.f, 0.f, 0.f);
#pragma unroll
    for (int j = 0; j < 2; ++j) {
        int idx = lane + 64 * j;
        float4 v = x4[idx];
        int kb = 4 * idx;
        float4 wa = w4[kb + 0], wb = w4[kb + 1], wc = w4[kb + 2], wd = w4[kb + 3];
        acc.x += v.x * wa.x + v.y * wb.x + v.z * wc.x + v.w * wd.x;
        acc.y += v.x * wa.y + v.y * wb.y + v.z * wc.y + v.w * wd.y;
        acc.z += v.x * wa.z + v.y * wb.z + v.z * wc.z + v.w * wd.z;
        acc.w += v.x * wa.w + v.y * wb.w + v.z * wc.w + v.w * wd.w;
    }
#pragma unroll
    for (int off = 32; off > 0; off >>= 1) {
        acc.x += __shfl_down(acc.x, off);
        acc.y += __shfl_down(acc.y, off);
        acc.z += __shfl_down(acc.z, off);
        acc.w += __shfl_down(acc.w, off);
    }
    if (lane == 0) {
        float di = dinv[row];
        ((float4*)h)[row] = make_float4(acc.x * di, acc.y * di, acc.z * di, acc.w * di);
    }
}

// Gather-accumulate for one node: 8 threads/node, 2x unrolled, dual accumulators.
__device__ __forceinline__ float4 gather8(const int* __restrict__ ebuf2,
                                          const float4* __restrict__ g4,
                                          int st, int c, int r) {
    float4 a0 = make_float4(0.f, 0.f, 0.f, 0.f);
    float4 a1 = make_float4(0.f, 0.f, 0.f, 0.f);
    int j = st + r, last = st + c;
    for (; j + 8 < last; j += 16) {
        int i0 = ebuf2[j];
        int i1 = ebuf2[j + 8];
        float4 f0 = g4[i0];
        float4 f1 = g4[i1];
        a0.x += f0.x; a0.y += f0.y; a0.z += f0.z; a0.w += f0.w;
        a1.x += f1.x; a1.y += f1.y; a1.z += f1.z; a1.w += f1.w;
    }
    if (j < last) {
        float4 f = g4[ebuf2[j]];
        a0.x += f.x; a0.y += f.y; a0.z += f.z; a0.w += f.w;
    }
    a0.x += a1.x; a0.y += a1.y; a0.z += a1.z; a0.w += a1.w;
    // octet reduce (lanes r^1, r^2, r^4 are in the same wave)
    a0.x += __shfl_xor(a0.x, 1); a0.y += __shfl_xor(a0.y, 1);
    a0.z += __shfl_xor(a0.z, 1); a0.w += __shfl_xor(a0.w, 1);
    a0.x += __shfl_xor(a0.x, 2); a0.y += __shfl_xor(a0.y, 2);
    a0.z += __shfl_xor(a0.z, 2); a0.w += __shfl_xor(a0.w, 2);
    a0.x += __shfl_xor(a0.x, 4); a0.y += __shfl_xor(a0.y, 4);
    a0.z += __shfl_xor(a0.z, 4); a0.w += __shfl_xor(a0.w, 4);
    return a0;
}

// Layer-1: agg = dinv_d*(sum hls[s] + hls[d]); h=relu(agg+b1); ts=(h@[Wmu|Wls])*dinv_d
__global__ __launch_bounds__(256) void k_agg1(const int* __restrict__ ebuf2,
                                              const int* __restrict__ nstart,
                                              const int* __restrict__ ncnt,
                                              const float* __restrict__ dinv,
                                              const float* __restrict__ hls,
                                              const float* __restrict__ b1,
                                              const float* __restrict__ Wmu,
                                              const float* __restrict__ Wls,
                                              float* __restrict__ ts) {
    int tid = threadIdx.x;
    int node = blockIdx.x * 32 + (tid >> 3);
    int r = tid & 7;
    if (node >= N_NODES) return;                 // octet-uniform exit
    const float4* g4 = (const float4*)hls;
    float4 a = gather8(ebuf2, g4, nstart[node], ncnt[node], r);
    if (r == 0) {
        float4 self = g4[node];
        float di = dinv[node];
        float h0 = fmaxf((a.x + self.x) * di + b1[0], 0.f);
        float h1 = fmaxf((a.y + self.y) * di + b1[1], 0.f);
        float h2 = fmaxf((a.z + self.z) * di + b1[2], 0.f);
        float h3 = fmaxf((a.w + self.w) * di + b1[3], 0.f);
        float4 o;
        o.x = (h0 * Wmu[0] + h1 * Wmu[2] + h2 * Wmu[4] + h3 * Wmu[6]) * di;
        o.y = (h0 * Wmu[1] + h1 * Wmu[3] + h2 * Wmu[5] + h3 * Wmu[7]) * di;
        o.z = (h0 * Wls[0] + h1 * Wls[2] + h2 * Wls[4] + h3 * Wls[6]) * di;
        o.w = (h0 * Wls[1] + h1 * Wls[3] + h2 * Wls[5] + h3 * Wls[7]) * di;
        ((float4*)ts)[node] = o;
    }
}

// Layer-2 aggregation on ts -> mu (out[0..2N)), logstd (out[2N..4N)).
__global__ __launch_bounds__(256) void k_agg2(const int* __restrict__ ebuf2,
                                              const int* __restrict__ nstart,
                                              const int* __restrict__ ncnt,
                                              const float* __restrict__ dinv,
                                              const float* __restrict__ ts,
                                              const float* __restrict__ bmu,
                                              const float* __restrict__ bls,
                                              float* __restrict__ out) {
    int tid = threadIdx.x;
    int node = blockIdx.x * 32 + (tid >> 3);
    int r = tid & 7;
    if (node >= N_NODES) return;
    const float4* g4 = (const float4*)ts;
    float4 a = gather8(ebuf2, g4, nstart[node], ncnt[node], r);
    if (r == 0) {
        float4 self = g4[node];
        float di = dinv[node];
        float2 mu = make_float2((a.x + self.x) * di + bmu[0],
                                (a.y + self.y) * di + bmu[1]);
        float2 ls = make_float2((a.z + self.z) * di + bls[0],
                                (a.w + self.w) * di + bls[1]);
        ((float2*)out)[node] = mu;
        ((float2*)(out + 2 * N_NODES))[node] = ls;
    }
}

extern "C" void kernel_launch(void* const* d_in, const int* in_sizes, int n_in,
                              void* d_out, int out_size, void* d_ws, size_t ws_size,
                              hipStream_t stream) {
    const float* x    = (const float*)d_in[0];
    const int*   ei   = (const int*)d_in[1];    // [2, E] int32: src row then dst row
    const float* W1   = (const float*)d_in[2];
    const float* b1   = (const float*)d_in[3];
    const float* Wmu  = (const float*)d_in[4];
    const float* bmu  = (const float*)d_in[5];
    const float* Wls  = (const float*)d_in[6];
    const float* bls  = (const float*)d_in[7];
    float* out = (float*)d_out;

    const int* src = ei;
    const int* dst = ei + N_EDGES;

    // workspace layout (~36 MB)
    char* p = (char*)d_ws;
    float* dinv   = (float*)p;  p += (size_t)N_NODES * 4;
    float* hls    = (float*)p;  p += (size_t)N_NODES * 16;
    float* ts     = (float*)p;  p += (size_t)N_NODES * 16;
    int*   nstart = (int*)p;    p += (size_t)N_NODES * 4;
    int*   ncnt   = (int*)p;    p += (size_t)N_NODES * 4;
    int*   bcur   = (int*)p;    p += (size_t)KC * 4;
    int*   ebuf1  = (int*)p;    p += (size_t)KC * CAP * 4;   // 16 MB
    int*   ebuf2  = (int*)p;    p += (size_t)KC * CAP * 4;   // 16 MB

    const int TB = 256;
    int gP1 = (N_EDGES + P1_CHUNK - 1) / P1_CHUNK;   // 782
    int gL  = (N_NODES + 3) / 4;                     // 25000
    int gA  = (N_NODES + 31) / 32;                   // 3125

    k_zero <<<(KC + TB - 1) / TB, TB, 0, stream>>>(bcur);
    k_part1<<<gP1, TB,   0, stream>>>(src, dst, bcur, ebuf1);
    k_part2<<<KC,  1024, 0, stream>>>(bcur, ebuf1, ebuf2, nstart, ncnt, dinv);
    k_lin1 <<<gL,  TB,   0, stream>>>(x, W1, dinv, hls);
    k_agg1 <<<gA,  TB,   0, stream>>>(ebuf2, nstart, ncnt, dinv, hls, b1, Wmu, Wls, ts);
    k_agg2 <<<gA,  TB,   0, stream>>>(ebuf2, nstart, ncnt, dinv, ts, bmu, bls, out);
}

// Round 6
// 396.397 us; speedup vs baseline: 4.3960x; 1.0008x over previous
//
#include <hip/hip_runtime.h>

// VariationalGCNEncoder: 2-layer GCN (512 -> 4 -> [2,2]), N=100k nodes, E=3.2M edges.
//
// R6: all fine-grained scattering moved to LDS; every global write is a coalesced
// contiguous burst (R2 evidence: scattered sub-line global writes cost ~45-90ns of
// line traffic each — k_scatter was 288us/195MB for a 12.8MB payload).
//
//   k_zero  : bcur[b] = b*CAP
//   k_part1 : tile->LDS 2-pass bucket sort (782 buckets of 128 nodes),
//             wave-per-bucket coalesced writeout to ebuf1
//   k_part2 : per-bucket 2-pass node sort in LDS, linear writeout to ebuf2;
//             emits nstart/ncnt/dinv
//   k_lin1  : hls = (x @ W1) * dinv[row]   (wave-per-row, float4)
//   k_agg1  : per-node CSR gather (8 thr/node, reg acc) -> relu -> ts=(h@[Wmu|Wls])*dinv
//   k_agg2  : same on ts -> mu, logstd -> d_out

constexpr int N_NODES = 100000;
constexpr int N_EDGES = 3200000;
constexpr int IN_CH   = 512;
constexpr int BK_SH   = 7;                       // 128 nodes per bucket
constexpr int BK_N    = 1 << BK_SH;              // 128
constexpr int KC      = (N_NODES + BK_N - 1) / BK_N;    // 782
constexpr int CAP     = 4608;                    // per-bucket capacity (mean 4092, sigma~64)
constexpr int T_TILE  = 13312;                   // edges per part1 tile (52 KB LDS)
constexpr int NT_P1   = (N_EDGES + T_TILE - 1) / T_TILE;  // 241

__global__ __launch_bounds__(256) void k_zero(int* __restrict__ bcur) {
    int i = blockIdx.x * blockDim.x + threadIdx.x;
    if (i < KC) bcur[i] = i * CAP;
}

// Tile-wise bucket sort with LDS staging; coalesced global writes only.
__global__ __launch_bounds__(512) void k_part1(const int* __restrict__ src,
                                               const int* __restrict__ dst,
                                               int* __restrict__ bcur,
                                               int* __restrict__ ebuf1) {
    __shared__ int sorted[T_TILE];   // 52 KB: bucket-sorted packed edges of this tile
    __shared__ int tstart[KC];       // tile-local exclusive bucket starts
    __shared__ int cur[KC];          // pass A: histogram; pass B: ranking cursor
    __shared__ int gbase[KC];        // reserved global base per bucket
    int tid = threadIdx.x;
    int e0 = blockIdx.x * T_TILE;
    int tcnt = min(T_TILE, N_EDGES - e0);

    for (int i = tid; i < KC; i += 512) cur[i] = 0;
    __syncthreads();

    // pass A: histogram dst buckets
    for (int j = tid; j < tcnt; j += 512) {
        int d = dst[e0 + j];
        if ((unsigned)d < (unsigned)N_NODES) atomicAdd(&cur[d >> BK_SH], 1);
    }
    __syncthreads();

    // scan cur -> tstart (782 entries, 2 per thread; temp in sorted[0..511])
    {
        int i0 = 2 * tid, i1 = 2 * tid + 1;
        int a0 = (i0 < KC) ? cur[i0] : 0;
        int a1 = (i1 < KC) ? cur[i1] : 0;
        int s = a0 + a1;
        sorted[tid] = s;
        __syncthreads();
        for (int off = 1; off < 512; off <<= 1) {
            int t = (tid >= off) ? sorted[tid - off] : 0;
            __syncthreads();
            sorted[tid] += t;
            __syncthreads();
        }
        int excl = sorted[tid] - s;
        if (i0 < KC) tstart[i0] = excl;
        if (i1 < KC) tstart[i1] = excl + a0;
        __syncthreads();
    }

    // reserve global space per bucket; convert cur -> ranking cursor
    for (int i = tid; i < KC; i += 512) {
        int c = cur[i];
        gbase[i] = c ? atomicAdd(&bcur[i], c) : 0;
        cur[i] = tstart[i];
    }
    __syncthreads();

    // pass B: rank + scatter into LDS (packed (s<<7)|(d&127); s < 2^17)
    for (int j = tid; j < tcnt; j += 512) {
        int s = src[e0 + j], d = dst[e0 + j];
        if ((unsigned)s < (unsigned)N_NODES && (unsigned)d < (unsigned)N_NODES) {
            int b = d >> BK_SH;
            int r = atomicAdd(&cur[b], 1);
            sorted[r] = (s << BK_SH) | (d & (BK_N - 1));
        }
    }
    __syncthreads();

    // writeout: wave-per-bucket, contiguous LDS run -> contiguous global segment
    int wv = tid >> 6, ln = tid & 63;
    for (int b = wv; b < KC; b += 8) {
        int st = tstart[b];
        int c  = cur[b] - st;               // bucket count in this tile
        int gb = gbase[b];
        int avail = (b + 1) * CAP - gb;     // capacity guard (unreachable statistically)
        if (avail < c) c = max(avail, 0);
        for (int j = ln; j < c; j += 64)
            ebuf1[gb + j] = sorted[st + j];
    }
}

// Per-bucket node sort: 2-pass in LDS, linear coalesced writeout; CSR + dinv.
__global__ __launch_bounds__(512) void k_part2(const int* __restrict__ bcur,
                                               const int* __restrict__ ebuf1,
                                               int* __restrict__ ebuf2,
                                               int* __restrict__ nstart,
                                               int* __restrict__ ncnt,
                                               float* __restrict__ dinv) {
    __shared__ int sorted[CAP];      // 18 KB
    __shared__ int hist[BK_N], excl[BK_N], curx[BK_N];
    int b = blockIdx.x, tid = threadIdx.x;
    int base = b * CAP;
    int cnt = min(bcur[b] - base, CAP);

    if (tid < BK_N) hist[tid] = 0;
    __syncthreads();
    // pass A: node histogram
    for (int j = tid; j < cnt; j += 512)
        atomicAdd(&hist[ebuf1[base + j] & (BK_N - 1)], 1);
    __syncthreads();
    // scan 128 entries (threads < 128 active, all threads hit barriers)
    if (tid < BK_N) excl[tid] = hist[tid];
    __syncthreads();
    for (int off = 1; off < BK_N; off <<= 1) {
        int t = (tid < BK_N && tid >= off) ? excl[tid - off] : 0;
        __syncthreads();
        if (tid < BK_N) excl[tid] += t;
        __syncthreads();
    }
    if (tid < BK_N) {
        int v = hist[tid];
        int ex = excl[tid] - v;             // exclusive
        excl[tid] = ex;
        curx[tid] = ex;
        int node = b * BK_N + tid;
        if (node < N_NODES) {
            nstart[node] = base + ex;
            ncnt[node]   = v;
            dinv[node]   = rsqrtf((float)(v + 1));   // +1 self loop
        }
    }
    __syncthreads();
    // pass B: rank + scatter into LDS (store src only; dst implied by position)
    for (int j = tid; j < cnt; j += 512) {
        int e = ebuf1[base + j];
        int r = atomicAdd(&curx[e & (BK_N - 1)], 1);
        sorted[r] = e >> BK_SH;
    }
    __syncthreads();
    // linear coalesced writeout
    for (int j = tid; j < cnt; j += 512)
        ebuf2[base + j] = sorted[j];
}

// hls[row] = (x[row,:] @ W1) * dinv[row] — one wave per row, float4 loads.
__global__ __launch_bounds__(256) void k_lin1(const float* __restrict__ x,
                                              const float* __restrict__ W1,
                                              const float* __restrict__ dinv,
                                              float* __restrict__ h) {
    int wave = threadIdx.x >> 6, lane = threadIdx.x & 63;
    int row = blockIdx.x * 4 + wave;
    if (row >= N_NODES) return;
    const float4* x4 = (const float4*)(x + (size_t)row * IN_CH);
    const float4* w4 = (const float4*)W1;
    float4 acc = make_float4(0.f, 0.f, 0.f, 0.f);
#pragma unroll
    for (int j = 0; j < 2; ++j) {
        int idx = lane + 64 * j;
        float4 v = x4[idx];
        int kb = 4 * idx;
        float4 wa = w4[kb + 0], wb = w4[kb + 1], wc = w4[kb + 2], wd = w4[kb + 3];
        acc.x += v.x * wa.x + v.y * wb.x + v.z * wc.x + v.w * wd.x;
        acc.y += v.x * wa.y + v.y * wb.y + v.z * wc.y + v.w * wd.y;
        acc.z += v.x * wa.z + v.y * wb.z + v.z * wc.z + v.w * wd.z;
        acc.w += v.x * wa.w + v.y * wb.w + v.z * wc.w + v.w * wd.w;
    }
#pragma unroll
    for (int off = 32; off > 0; off >>= 1) {
        acc.x += __shfl_down(acc.x, off);
        acc.y += __shfl_down(acc.y, off);
        acc.z += __shfl_down(acc.z, off);
        acc.w += __shfl_down(acc.w, off);
    }
    if (lane == 0) {
        float di = dinv[row];
        ((float4*)h)[row] = make_float4(acc.x * di, acc.y * di, acc.z * di, acc.w * di);
    }
}

// Gather-accumulate for one node: 8 threads/node, 2x unrolled, dual accumulators.
__device__ __forceinline__ float4 gather8(const int* __restrict__ ebuf2,
                                          const float4* __restrict__ g4,
                                          int st, int c, int r) {
    float4 a0 = make_float4(0.f, 0.f, 0.f, 0.f);
    float4 a1 = make_float4(0.f, 0.f, 0.f, 0.f);
    int j = st + r, last = st + c;
    for (; j + 8 < last; j += 16) {
        int i0 = ebuf2[j];
        int i1 = ebuf2[j + 8];
        float4 f0 = g4[i0];
        float4 f1 = g4[i1];
        a0.x += f0.x; a0.y += f0.y; a0.z += f0.z; a0.w += f0.w;
        a1.x += f1.x; a1.y += f1.y; a1.z += f1.z; a1.w += f1.w;
    }
    if (j < last) {
        float4 f = g4[ebuf2[j]];
        a0.x += f.x; a0.y += f.y; a0.z += f.z; a0.w += f.w;
    }
    a0.x += a1.x; a0.y += a1.y; a0.z += a1.z; a0.w += a1.w;
    a0.x += __shfl_xor(a0.x, 1); a0.y += __shfl_xor(a0.y, 1);
    a0.z += __shfl_xor(a0.z, 1); a0.w += __shfl_xor(a0.w, 1);
    a0.x += __shfl_xor(a0.x, 2); a0.y += __shfl_xor(a0.y, 2);
    a0.z += __shfl_xor(a0.z, 2); a0.w += __shfl_xor(a0.w, 2);
    a0.x += __shfl_xor(a0.x, 4); a0.y += __shfl_xor(a0.y, 4);
    a0.z += __shfl_xor(a0.z, 4); a0.w += __shfl_xor(a0.w, 4);
    return a0;
}

// Layer-1: agg = dinv_d*(sum hls[s] + hls[d]); h=relu(agg+b1); ts=(h@[Wmu|Wls])*dinv_d
__global__ __launch_bounds__(256) void k_agg1(const int* __restrict__ ebuf2,
                                              const int* __restrict__ nstart,
                                              const int* __restrict__ ncnt,
                                              const float* __restrict__ dinv,
                                              const float* __restrict__ hls,
                                              const float* __restrict__ b1,
                                              const float* __restrict__ Wmu,
                                              const float* __restrict__ Wls,
                                              float* __restrict__ ts) {
    int tid = threadIdx.x;
    int node = blockIdx.x * 32 + (tid >> 3);
    int r = tid & 7;
    if (node >= N_NODES) return;                 // octet-uniform exit
    const float4* g4 = (const float4*)hls;
    float4 a = gather8(ebuf2, g4, nstart[node], ncnt[node], r);
    if (r == 0) {
        float4 self = g4[node];
        float di = dinv[node];
        float h0 = fmaxf((a.x + self.x) * di + b1[0], 0.f);
        float h1 = fmaxf((a.y + self.y) * di + b1[1], 0.f);
        float h2 = fmaxf((a.z + self.z) * di + b1[2], 0.f);
        float h3 = fmaxf((a.w + self.w) * di + b1[3], 0.f);
        float4 o;
        o.x = (h0 * Wmu[0] + h1 * Wmu[2] + h2 * Wmu[4] + h3 * Wmu[6]) * di;
        o.y = (h0 * Wmu[1] + h1 * Wmu[3] + h2 * Wmu[5] + h3 * Wmu[7]) * di;
        o.z = (h0 * Wls[0] + h1 * Wls[2] + h2 * Wls[4] + h3 * Wls[6]) * di;
        o.w = (h0 * Wls[1] + h1 * Wls[3] + h2 * Wls[5] + h3 * Wls[7]) * di;
        ((float4*)ts)[node] = o;
    }
}

// Layer-2 aggregation on ts -> mu (out[0..2N)), logstd (out[2N..4N)).
__global__ __launch_bounds__(256) void k_agg2(const int* __restrict__ ebuf2,
                                              const int* __restrict__ nstart,
                                              const int* __restrict__ ncnt,
                                              const float* __restrict__ dinv,
                                              const float* __restrict__ ts,
                                              const float* __restrict__ bmu,
                                              const float* __restrict__ bls,
                                              float* __restrict__ out) {
    int tid = threadIdx.x;
    int node = blockIdx.x * 32 + (tid >> 3);
    int r = tid & 7;
    if (node >= N_NODES) return;
    const float4* g4 = (const float4*)ts;
    float4 a = gather8(ebuf2, g4, nstart[node], ncnt[node], r);
    if (r == 0) {
        float4 self = g4[node];
        float di = dinv[node];
        float2 mu = make_float2((a.x + self.x) * di + bmu[0],
                                (a.y + self.y) * di + bmu[1]);
        float2 ls = make_float2((a.z + self.z) * di + bls[0],
                                (a.w + self.w) * di + bls[1]);
        ((float2*)out)[node] = mu;
        ((float2*)(out + 2 * N_NODES))[node] = ls;
    }
}

extern "C" void kernel_launch(void* const* d_in, const int* in_sizes, int n_in,
                              void* d_out, int out_size, void* d_ws, size_t ws_size,
                              hipStream_t stream) {
    const float* x    = (const float*)d_in[0];
    const int*   ei   = (const int*)d_in[1];    // [2, E] int32: src row then dst row
    const float* W1   = (const float*)d_in[2];
    const float* b1   = (const float*)d_in[3];
    const float* Wmu  = (const float*)d_in[4];
    const float* bmu  = (const float*)d_in[5];
    const float* Wls  = (const float*)d_in[6];
    const float* bls  = (const float*)d_in[7];
    float* out = (float*)d_out;

    const int* src = ei;
    const int* dst = ei + N_EDGES;

    // workspace layout (~34 MB)
    char* p = (char*)d_ws;
    float* dinv   = (float*)p;  p += (size_t)N_NODES * 4;
    float* hls    = (float*)p;  p += (size_t)N_NODES * 16;
    float* ts     = (float*)p;  p += (size_t)N_NODES * 16;
    int*   nstart = (int*)p;    p += (size_t)N_NODES * 4;
    int*   ncnt   = (int*)p;    p += (size_t)N_NODES * 4;
    int*   bcur   = (int*)p;    p += (size_t)KC * 4;
    int*   ebuf1  = (int*)p;    p += (size_t)KC * CAP * 4;   // 14.4 MB
    int*   ebuf2  = (int*)p;    p += (size_t)KC * CAP * 4;   // 14.4 MB

    const int TB = 256;
    int gL = (N_NODES + 3) / 4;       // 25000
    int gA = (N_NODES + 31) / 32;     // 3125

    k_zero <<<(KC + TB - 1) / TB, TB, 0, stream>>>(bcur);
    k_part1<<<NT_P1, 512, 0, stream>>>(src, dst, bcur, ebuf1);
    k_part2<<<KC,    512, 0, stream>>>(bcur, ebuf1, ebuf2, nstart, ncnt, dinv);
    k_lin1 <<<gL,    TB,  0, stream>>>(x, W1, dinv, hls);
    k_agg1 <<<gA,    TB,  0, stream>>>(ebuf2, nstart, ncnt, dinv, hls, b1, Wmu, Wls, ts);
    k_agg2 <<<gA,    TB,  0, stream>>>(ebuf2, nstart, ncnt, dinv, ts, bmu, bls, out);
}